// Round 7
// baseline (760.082 us; speedup 1.0000x reference)
//
#include <hip/hip_runtime.h>
#include <math.h>

typedef unsigned short us;
typedef __attribute__((ext_vector_type(8))) short frag8;
typedef __attribute__((ext_vector_type(4))) float f4;

#define B_   2
#define T_   1024
#define DM_  1024
#define D_   2048
#define N_   16
#define DTR_ 128
#define NDBC 160           // DTR + 2N
#define ROWS (B_*T_)       // 2048
#define EPS_ 1e-6f
#define NCH  32            // scan chunks per channel
#define CLEN (T_/NCH)      // 32 steps per chunk

__device__ __forceinline__ float us2f(us s){
    return __uint_as_float(((unsigned int)s) << 16);
}
__device__ __forceinline__ us f2us(float f){   // RTN-even fp32->bf16
    unsigned int u = __float_as_uint(f);
    return (us)((u + 0x7FFF + ((u >> 16) & 1)) >> 16);
}

// ------------- weight prep: transpose fp32 [R][C] -> bf16 [C][R] -------------
__global__ __launch_bounds__(256) void transpose_bf(const float* __restrict__ in,
                                                    us* __restrict__ out, int R, int C)
{
    __shared__ us tile[32][33];
    int c0 = blockIdx.x * 32, r0 = blockIdx.y * 32;
    int tx = threadIdx.x, ty = threadIdx.y;   // 32 x 8
    for (int i = ty; i < 32; i += 8) {
        int r = r0 + i, c = c0 + tx;
        tile[i][tx] = (r < R && c < C) ? f2us(in[(size_t)r * C + c]) : (us)0;
    }
    __syncthreads();
    for (int i = ty; i < 32; i += 8) {
        int c = c0 + i, r = r0 + tx;
        if (c < C && r < R) out[(size_t)c * R + r] = tile[tx][i];
    }
}

// ---------------- RMS scale: x (fp32) -> scale[row] ----------------
__global__ __launch_bounds__(256) void rms_scale_kernel(const float* __restrict__ x,
                                                        float* __restrict__ scale)
{
    const int row = blockIdx.x;
    const float* xr = x + (size_t)row * DM_;
    const int tid = threadIdx.x;
    float ss = 0.f;
#pragma unroll
    for (int i = 0; i < 4; ++i) { float v = xr[tid + i*256]; ss += v*v; }
#pragma unroll
    for (int off = 32; off >= 1; off >>= 1) ss += __shfl_xor(ss, off, 64);
    __shared__ float red[4];
    if ((tid & 63) == 0) red[tid >> 6] = ss;
    __syncthreads();
    if (tid == 0) {
        float tot = red[0] + red[1] + red[2] + red[3];
        scale[row] = rsqrtf(tot / (float)DM_ + EPS_);
    }
}

// ---------------- rmsnorm apply -> bf16 A for in_proj ----------------
__global__ __launch_bounds__(256) void hbf_kernel(const float* __restrict__ x,
                                                  const float* __restrict__ scale,
                                                  const float* __restrict__ rms_w,
                                                  us* __restrict__ hbf)
{
    int idx = blockIdx.x * 256 + threadIdx.x;       // ROWS*DM
    int row = idx >> 10, k = idx & (DM_ - 1);
    hbf[idx] = f2us(x[idx] * scale[row] * rms_w[k]);
}

// ---------- MFMA GEMM: C[M,N] = A[M,K](bf16) * Bt[N,K](bf16)^T + bias --------
// 128x128 tile / block of 4 waves; each wave 64x64 via 4x4 mfma_f32_16x16x32_bf16.
// EPI 0: store fp32. 1: softplus->fp32. 2: +resid->fp32. 3: fp32 + bf16 aux (col<DTR).
template<int EPI>
__global__ __launch_bounds__(256) void mgemm(
    const us*    __restrict__ A,     // [M][K]
    const us*    __restrict__ Bt,    // [N][K]
    const float* __restrict__ bias,  // [N]
    float*       __restrict__ Cf,    // [M][N]
    us*          __restrict__ Caux,  // EPI==3
    const float* __restrict__ resid, // EPI==2
    int M, int N, int K)
{
    __shared__ us As[128][72];   // 72-short rows: b128 frag reads are 2-way (free)
    __shared__ us Bs[128][72];
    const int tid = threadIdx.x;
    const int bm = blockIdx.y * 128;
    const int bn = blockIdx.x * 128;
    const int w = tid >> 6, lane = tid & 63;
    const int wr = w >> 1, wc = w & 1;
    const int m16 = lane & 15, quad = lane >> 4;

    f4 acc[4][4];
#pragma unroll
    for (int i = 0; i < 4; ++i)
#pragma unroll
        for (int j = 0; j < 4; ++j)
            acc[i][j] = (f4){0.f, 0.f, 0.f, 0.f};

    for (int k0 = 0; k0 < K; k0 += 64) {
        __syncthreads();   // prior iter's frag reads done before overwrite
#pragma unroll
        for (int i = 0; i < 4; ++i) {
            int chunk = i * 256 + tid;           // 1024 chunks of 16B
            int row = chunk >> 3, c8 = (chunk & 7) * 8;
            int4 va = *(const int4*)(A + (size_t)(bm + row) * K + k0 + c8);
            *(int4*)&As[row][c8] = va;
            int nrow = bn + row;
            int4 vb = make_int4(0, 0, 0, 0);
            if (nrow < N) vb = *(const int4*)(Bt + (size_t)nrow * K + k0 + c8);
            *(int4*)&Bs[row][c8] = vb;
        }
        __syncthreads();
#pragma unroll
        for (int ks = 0; ks < 64; ks += 32) {
            frag8 af[4], bfr[4];
#pragma unroll
            for (int i = 0; i < 4; ++i)
                af[i] = *(const frag8*)&As[wr*64 + i*16 + m16][ks + quad*8];
#pragma unroll
            for (int j = 0; j < 4; ++j)
                bfr[j] = *(const frag8*)&Bs[wc*64 + j*16 + m16][ks + quad*8];
#pragma unroll
            for (int i = 0; i < 4; ++i)
#pragma unroll
                for (int j = 0; j < 4; ++j)
                    acc[i][j] = __builtin_amdgcn_mfma_f32_16x16x32_bf16(af[i], bfr[j], acc[i][j], 0, 0, 0);
        }
    }

#pragma unroll
    for (int i = 0; i < 4; ++i) {
#pragma unroll
        for (int j = 0; j < 4; ++j) {
            int col = bn + wc*64 + j*16 + m16;
            if (col >= N) continue;
            float bv = bias[col];
#pragma unroll
            for (int r = 0; r < 4; ++r) {
                int row = bm + wr*64 + i*16 + quad*4 + r;
                float v = acc[i][j][r] + bv;
                if constexpr (EPI == 1) v = fmaxf(v, 0.f) + log1pf(expf(-fabsf(v)));
                if constexpr (EPI == 2) v += resid[(size_t)row * N + col];
                Cf[(size_t)row * N + col] = v;
                if constexpr (EPI == 3) {
                    if (col < DTR_) Caux[(size_t)row * DTR_ + col] = f2us(v);
                }
            }
        }
    }
}

// ---------------- depthwise causal conv (K=4) + SiLU -> bf16 -----------------
__global__ __launch_bounds__(256) void conv_silu_kernel(
    const float* __restrict__ proj,
    const float* __restrict__ cw,
    const float* __restrict__ cb,
    us*          __restrict__ x1cb)
{
    int idx = blockIdx.x * 256 + threadIdx.x;   // ROWS*D
    int d   = idx & (D_ - 1);
    int row = idx >> 11;
    int t   = row & (T_ - 1);
    const float* base = proj + (size_t)row * (2*D_) + d;
    float acc = cb[d];
    float w0 = cw[d*4+0], w1 = cw[d*4+1], w2 = cw[d*4+2], w3 = cw[d*4+3];
    acc = fmaf(w3, base[0], acc);
    if (t >= 1) acc = fmaf(w2, base[-(2*D_)],   acc);
    if (t >= 2) acc = fmaf(w1, base[-2*(2*D_)], acc);
    if (t >= 3) acc = fmaf(w0, base[-3*(2*D_)], acc);
    float sg = 1.f / (1.f + __expf(-acc));
    x1cb[idx] = f2us(acc * sg);
}

// ------- chunked selective scan + gate, one block per (b,d) channel ----------
// 512 threads = NCH(32) chunks x N(16) states. Phase 1: local scan from h=0,
// caching a_j=exp(dv*A) and b_j=dv*B*x in registers (full unroll). Phase 2:
// LDS chunk-prefix. Phase 3: register-replay with true h0 + C-contraction
// (16-lane shfl) + SiLU gate. delta/x reads are 16-lane broadcasts; B/C reads
// coalesced. No LDS staging needed (each input read exactly once).
__global__ __launch_bounds__(512, 4) void scan_block_kernel(
    const float* __restrict__ delta,
    const us*    __restrict__ x1cb,
    const float* __restrict__ dbc,    // [...,128:144]=Bm [...,144:160]=Cm
    const float* __restrict__ A_log,
    const float* __restrict__ proj,   // g at col D+d
    us*          __restrict__ ybf)    // y*silu(g), bf16
{
    __shared__ float Pl[NCH][N_];
    __shared__ float Sl[NCH][N_];

    const int tid = threadIdx.x;
    const int d = blockIdx.x & (D_ - 1);
    const int b = blockIdx.x >> 11;
    const int n = tid & 15;
    const int c = tid >> 4;            // chunk 0..31
    const size_t rb = (size_t)b * T_ + (size_t)c * CLEN;

    const float a_coef = -__expf(A_log[d * N_ + n]);

    float areg[CLEN], breg[CLEN];
    float P = 1.f, S = 0.f;
#pragma unroll
    for (int j = 0; j < CLEN; ++j) {
        size_t r = rb + j;
        float dv = delta[r * D_ + d];            // broadcast across 16 lanes
        float xv = us2f(x1cb[r * D_ + d]);       // broadcast
        float Bv = dbc[r * NDBC + DTR_ + n];     // coalesced 16 lanes
        float a = __expf(dv * a_coef);
        float bb = dv * Bv * xv;
        areg[j] = a;
        breg[j] = bb;
        P *= a;
        S = fmaf(a, S, bb);
    }
    Pl[c][n] = P;
    Sl[c][n] = S;
    __syncthreads();

    float h = 0.f;
    for (int c2 = 0; c2 < c; ++c2)
        h = fmaf(Pl[c2][n], h, Sl[c2][n]);

#pragma unroll
    for (int j = 0; j < CLEN; ++j) {
        size_t r = rb + j;
        float Cv = dbc[r * NDBC + DTR_ + N_ + n];
        h = fmaf(areg[j], h, breg[j]);
        float part = h * Cv;
        part += __shfl_xor(part, 1, 16);
        part += __shfl_xor(part, 2, 16);
        part += __shfl_xor(part, 4, 16);
        part += __shfl_xor(part, 8, 16);
        if (n == 0) {
            float g = proj[r * (2*D_) + D_ + d];
            float sg = 1.f / (1.f + __expf(-g));
            ybf[r * D_ + d] = f2us(part * g * sg);
        }
    }
}

extern "C" void kernel_launch(void* const* d_in, const int* in_sizes, int n_in,
                              void* d_out, int out_size, void* d_ws, size_t ws_size,
                              hipStream_t stream)
{
    const float* x      = (const float*)d_in[0];
    const float* rms_w  = (const float*)d_in[1];
    const float* in_W   = (const float*)d_in[2];
    const float* in_b   = (const float*)d_in[3];
    const float* conv_w = (const float*)d_in[4];
    const float* conv_b = (const float*)d_in[5];
    const float* A_log  = (const float*)d_in[6];
    const float* dbc_W  = (const float*)d_in[7];
    const float* dbc_b  = (const float*)d_in[8];
    const float* dup_W  = (const float*)d_in[9];
    const float* dup_b  = (const float*)d_in[10];
    const float* out_W  = (const float*)d_in[11];
    const float* out_b  = (const float*)d_in[12];
    float* out = (float*)d_out;

    // ---- workspace layout (86.9 MB; 89.3 MB proven available in R1) ----
    float* ws    = (float*)d_ws;
    float* proj  = ws;                            // 8M f   (x1pre | g)
    float* dbcB  = proj  + (size_t)ROWS*2*D_;     // 327680 f
    float* delta = dbcB  + (size_t)ROWS*NDBC;     // 4M f
    float* scale = delta + (size_t)ROWS*D_;       // 2048 f
    us* hbf   = (us*)(scale + ROWS);              // 2M us
    us* x1cb  = hbf   + (size_t)ROWS*DM_;         // 4M us
    us* dtrb  = x1cb  + (size_t)ROWS*D_;          // 256K us
    us* ybf   = dtrb  + (size_t)ROWS*DTR_;        // 4M us
    us* inWt  = ybf   + (size_t)ROWS*D_;          // 4M us   [4096][1024]
    us* dbcWt = inWt  + (size_t)2*D_*DM_;         // 320K us [160][2048]
    us* dupWt = dbcWt + (size_t)NDBC*D_;          // 256K us [2048][128]
    us* outWt = dupWt + (size_t)D_*DTR_;          // 2M us   [1024][2048]

    dim3 tb(32, 8);
    // weight prep: fp32 [R][C] -> bf16 [C][R]
    transpose_bf<<<dim3(4096/32, 1024/32), tb, 0, stream>>>(in_W,  inWt,  DM_, 2*D_);
    transpose_bf<<<dim3(5,      2048/32), tb, 0, stream>>>(dbc_W, dbcWt, D_,  NDBC);
    transpose_bf<<<dim3(2048/32,      4), tb, 0, stream>>>(dup_W, dupWt, DTR_, D_);
    transpose_bf<<<dim3(1024/32, 2048/32), tb, 0, stream>>>(out_W, outWt, D_,  DM_);

    // rmsnorm -> bf16 A
    rms_scale_kernel<<<ROWS, 256, 0, stream>>>(x, scale);
    hbf_kernel<<<(ROWS*DM_)/256, 256, 0, stream>>>(x, scale, rms_w, hbf);

    // in_proj: proj = h @ in_W + in_b      [2048 x 4096], K=1024
    mgemm<0><<<dim3(4096/128, ROWS/128), 256, 0, stream>>>(
        hbf, inWt, in_b, proj, nullptr, nullptr, ROWS, 2*D_, DM_);

    // conv + silu -> x1c (bf16)
    conv_silu_kernel<<<(ROWS*D_)/256, 256, 0, stream>>>(proj, conv_w, conv_b, x1cb);

    // dbc = x1c @ dbc_W + dbc_b            [2048 x 160], K=2048 (+bf16 aux of cols<128)
    mgemm<3><<<dim3(2, ROWS/128), 256, 0, stream>>>(
        x1cb, dbcWt, dbc_b, dbcB, dtrb, nullptr, ROWS, NDBC, D_);

    // delta = softplus(dtr @ dup_W + dup_b)  [2048 x 2048], K=128
    mgemm<1><<<dim3(2048/128, ROWS/128), 256, 0, stream>>>(
        dtrb, dupWt, dup_b, delta, nullptr, nullptr, ROWS, D_, DTR_);

    // chunked selective scan + gate -> ybf
    scan_block_kernel<<<B_*D_, 512, 0, stream>>>(delta, x1cb, dbcB, A_log, proj, ybf);

    // out = y @ out_W + out_b + residual   [2048 x 1024], K=2048
    mgemm<2><<<dim3(1024/128, ROWS/128), 256, 0, stream>>>(
        ybf, outWt, out_b, out, nullptr, x, ROWS, DM_, D_);
}

// Round 8
// 491.428 us; speedup vs baseline: 1.5467x; 1.5467x over previous
//
#include <hip/hip_runtime.h>
#include <math.h>

typedef unsigned short us;
typedef __attribute__((ext_vector_type(8))) short frag8;
typedef __attribute__((ext_vector_type(4))) float f4;

#define B_   2
#define T_   1024
#define DM_  1024
#define D_   2048
#define N_   16
#define DTR_ 128
#define NDBC 160           // DTR + 2N
#define ROWS (B_*T_)       // 2048
#define EPS_ 1e-6f
#define NCH  16            // scan chunks per channel
#define CLEN (T_/NCH)      // 64 steps per chunk

__device__ __forceinline__ float us2f(us s){
    return __uint_as_float(((unsigned int)s) << 16);
}
__device__ __forceinline__ us f2us(float f){   // RTN-even fp32->bf16
    unsigned int u = __float_as_uint(f);
    return (us)((u + 0x7FFF + ((u >> 16) & 1)) >> 16);
}

// ------------- weight prep: transpose fp32 [R][C] -> bf16 [C][R] -------------
__global__ __launch_bounds__(256) void transpose_bf(const float* __restrict__ in,
                                                    us* __restrict__ out, int R, int C)
{
    __shared__ us tile[32][33];
    int c0 = blockIdx.x * 32, r0 = blockIdx.y * 32;
    int tx = threadIdx.x, ty = threadIdx.y;   // 32 x 8
    for (int i = ty; i < 32; i += 8) {
        int r = r0 + i, c = c0 + tx;
        tile[i][tx] = (r < R && c < C) ? f2us(in[(size_t)r * C + c]) : (us)0;
    }
    __syncthreads();
    for (int i = ty; i < 32; i += 8) {
        int c = c0 + i, r = r0 + tx;
        if (c < C && r < R) out[(size_t)c * R + r] = tile[tx][i];
    }
}

// ---------------- RMS scale: x (fp32) -> scale[row] ----------------
__global__ __launch_bounds__(256) void rms_scale_kernel(const float* __restrict__ x,
                                                        float* __restrict__ scale)
{
    const int row = blockIdx.x;
    const float* xr = x + (size_t)row * DM_;
    const int tid = threadIdx.x;
    float ss = 0.f;
#pragma unroll
    for (int i = 0; i < 4; ++i) { float v = xr[tid + i*256]; ss += v*v; }
#pragma unroll
    for (int off = 32; off >= 1; off >>= 1) ss += __shfl_xor(ss, off, 64);
    __shared__ float red[4];
    if ((tid & 63) == 0) red[tid >> 6] = ss;
    __syncthreads();
    if (tid == 0) {
        float tot = red[0] + red[1] + red[2] + red[3];
        scale[row] = rsqrtf(tot / (float)DM_ + EPS_);
    }
}

// ---------------- rmsnorm apply -> bf16 A for in_proj ----------------
__global__ __launch_bounds__(256) void hbf_kernel(const float* __restrict__ x,
                                                  const float* __restrict__ scale,
                                                  const float* __restrict__ rms_w,
                                                  us* __restrict__ hbf)
{
    int idx = blockIdx.x * 256 + threadIdx.x;       // ROWS*DM
    int row = idx >> 10, k = idx & (DM_ - 1);
    hbf[idx] = f2us(x[idx] * scale[row] * rms_w[k]);
}

// ---------- MFMA GEMM: C[M,N] = A[M,K](bf16) * Bt[N,K](bf16)^T + bias --------
// 128x128 tile / block of 4 waves; each wave 64x64 via 4x4 mfma_f32_16x16x32_bf16.
// EPI 0: store fp32. 1: softplus->fp32. 2: +resid->fp32. 3: fp32 + bf16 aux (col<DTR).
template<int EPI>
__global__ __launch_bounds__(256) void mgemm(
    const us*    __restrict__ A,     // [M][K]
    const us*    __restrict__ Bt,    // [N][K]
    const float* __restrict__ bias,  // [N]
    float*       __restrict__ Cf,    // [M][N]
    us*          __restrict__ Caux,  // EPI==3
    const float* __restrict__ resid, // EPI==2
    int M, int N, int K)
{
    __shared__ us As[128][72];   // 72-short rows: b128 frag reads are 2-way (free)
    __shared__ us Bs[128][72];
    const int tid = threadIdx.x;
    const int bm = blockIdx.y * 128;
    const int bn = blockIdx.x * 128;
    const int w = tid >> 6, lane = tid & 63;
    const int wr = w >> 1, wc = w & 1;
    const int m16 = lane & 15, quad = lane >> 4;

    f4 acc[4][4];
#pragma unroll
    for (int i = 0; i < 4; ++i)
#pragma unroll
        for (int j = 0; j < 4; ++j)
            acc[i][j] = (f4){0.f, 0.f, 0.f, 0.f};

    for (int k0 = 0; k0 < K; k0 += 64) {
        __syncthreads();   // prior iter's frag reads done before overwrite
#pragma unroll
        for (int i = 0; i < 4; ++i) {
            int chunk = i * 256 + tid;           // 1024 chunks of 16B
            int row = chunk >> 3, c8 = (chunk & 7) * 8;
            int4 va = *(const int4*)(A + (size_t)(bm + row) * K + k0 + c8);
            *(int4*)&As[row][c8] = va;
            int nrow = bn + row;
            int4 vb = make_int4(0, 0, 0, 0);
            if (nrow < N) vb = *(const int4*)(Bt + (size_t)nrow * K + k0 + c8);
            *(int4*)&Bs[row][c8] = vb;
        }
        __syncthreads();
#pragma unroll
        for (int ks = 0; ks < 64; ks += 32) {
            frag8 af[4], bfr[4];
#pragma unroll
            for (int i = 0; i < 4; ++i)
                af[i] = *(const frag8*)&As[wr*64 + i*16 + m16][ks + quad*8];
#pragma unroll
            for (int j = 0; j < 4; ++j)
                bfr[j] = *(const frag8*)&Bs[wc*64 + j*16 + m16][ks + quad*8];
#pragma unroll
            for (int i = 0; i < 4; ++i)
#pragma unroll
                for (int j = 0; j < 4; ++j)
                    acc[i][j] = __builtin_amdgcn_mfma_f32_16x16x32_bf16(af[i], bfr[j], acc[i][j], 0, 0, 0);
        }
    }

#pragma unroll
    for (int i = 0; i < 4; ++i) {
#pragma unroll
        for (int j = 0; j < 4; ++j) {
            int col = bn + wc*64 + j*16 + m16;
            if (col >= N) continue;
            float bv = bias[col];
#pragma unroll
            for (int r = 0; r < 4; ++r) {
                int row = bm + wr*64 + i*16 + quad*4 + r;
                float v = acc[i][j][r] + bv;
                if constexpr (EPI == 1) v = fmaxf(v, 0.f) + log1pf(expf(-fabsf(v)));
                if constexpr (EPI == 2) v += resid[(size_t)row * N + col];
                Cf[(size_t)row * N + col] = v;
                if constexpr (EPI == 3) {
                    if (col < DTR_) Caux[(size_t)row * DTR_ + col] = f2us(v);
                }
            }
        }
    }
}

// ---------------- depthwise causal conv (K=4) + SiLU -> bf16 -----------------
__global__ __launch_bounds__(256) void conv_silu_kernel(
    const float* __restrict__ proj,
    const float* __restrict__ cw,
    const float* __restrict__ cb,
    us*          __restrict__ x1cb)
{
    int idx = blockIdx.x * 256 + threadIdx.x;   // ROWS*D
    int d   = idx & (D_ - 1);
    int row = idx >> 11;
    int t   = row & (T_ - 1);
    const float* base = proj + (size_t)row * (2*D_) + d;
    float acc = cb[d];
    float w0 = cw[d*4+0], w1 = cw[d*4+1], w2 = cw[d*4+2], w3 = cw[d*4+3];
    acc = fmaf(w3, base[0], acc);
    if (t >= 1) acc = fmaf(w2, base[-(2*D_)],   acc);
    if (t >= 2) acc = fmaf(w1, base[-2*(2*D_)], acc);
    if (t >= 3) acc = fmaf(w0, base[-3*(2*D_)], acc);
    float sg = 1.f / (1.f + __expf(-acc));
    x1cb[idx] = f2us(acc * sg);
}

// ------- chunked selective scan + gate, one block per (b,d) channel ----------
// 256 threads = NCH(16) chunks x N(16) states. R6-proven structure (no per-
// thread arrays -> no spill; VGPR ~24). Phase 1: local scan (P,S) from LDS-
// staged inputs. Phase 2: LDS chunk-prefix. Phase 3: re-scan with true h0,
// C-contraction via 16-lane shfl, fused SiLU gate. __expf throughout (the
// libm expf was the VALU hog at R6's 85% VALUBusy).
__global__ __launch_bounds__(256) void scan_block_kernel(
    const float* __restrict__ delta,
    const us*    __restrict__ x1cb,
    const float* __restrict__ dbc,    // [...,128:144]=Bm [...,144:160]=Cm
    const float* __restrict__ A_log,
    const float* __restrict__ proj,   // g at col D+d
    us*          __restrict__ ybf)    // y*silu(g), bf16
{
    __shared__ float dvs[T_ + NCH];   // swizzle f(t)=t+(t>>6)
    __shared__ float xvs[T_ + NCH];
    __shared__ float gs [T_ + NCH];
    __shared__ float Pl[NCH][N_];
    __shared__ float Sl[NCH][N_];

    const int tid = threadIdx.x;
    const int d = blockIdx.x & (D_ - 1);
    const int b = blockIdx.x >> 11;
    const int n = tid & 15;
    const int c = tid >> 4;
    const size_t rb = (size_t)b * T_;

    for (int i = tid; i < T_; i += 256) {
        int fi = i + (i >> 6);
        dvs[fi] = delta[(rb + i) * D_ + d];
        xvs[fi] = us2f(x1cb[(rb + i) * D_ + d]);
        gs [fi] = proj[(rb + i) * (2*D_) + D_ + d];
    }
    const float a_coef = -__expf(A_log[d * N_ + n]);
    __syncthreads();

    float P = 1.f, S = 0.f;
    const int t0 = c * CLEN;
    for (int j = 0; j < CLEN; ++j) {
        int t = t0 + j;
        int ft = t + (t >> 6);
        float dv = dvs[ft];
        float xv = xvs[ft];
        float Bv = dbc[(rb + t) * NDBC + DTR_ + n];
        float a = __expf(dv * a_coef);
        P *= a;
        S = fmaf(a, S, dv * Bv * xv);
    }
    Pl[c][n] = P;
    Sl[c][n] = S;
    __syncthreads();

    float h = 0.f;
    for (int c2 = 0; c2 < c; ++c2)
        h = fmaf(Pl[c2][n], h, Sl[c2][n]);

    for (int j = 0; j < CLEN; ++j) {
        int t = t0 + j;
        int ft = t + (t >> 6);
        float dv = dvs[ft];
        float xv = xvs[ft];
        size_t r = rb + t;
        float Bv = dbc[r * NDBC + DTR_ + n];
        float Cv = dbc[r * NDBC + DTR_ + N_ + n];
        float a = __expf(dv * a_coef);
        h = fmaf(a, h, dv * Bv * xv);
        float part = h * Cv;
        part += __shfl_xor(part, 1, 16);
        part += __shfl_xor(part, 2, 16);
        part += __shfl_xor(part, 4, 16);
        part += __shfl_xor(part, 8, 16);
        if (n == 0) {
            float g = gs[ft];
            float sg = 1.f / (1.f + __expf(-g));
            ybf[r * D_ + d] = f2us(part * g * sg);
        }
    }
}

extern "C" void kernel_launch(void* const* d_in, const int* in_sizes, int n_in,
                              void* d_out, int out_size, void* d_ws, size_t ws_size,
                              hipStream_t stream)
{
    const float* x      = (const float*)d_in[0];
    const float* rms_w  = (const float*)d_in[1];
    const float* in_W   = (const float*)d_in[2];
    const float* in_b   = (const float*)d_in[3];
    const float* conv_w = (const float*)d_in[4];
    const float* conv_b = (const float*)d_in[5];
    const float* A_log  = (const float*)d_in[6];
    const float* dbc_W  = (const float*)d_in[7];
    const float* dbc_b  = (const float*)d_in[8];
    const float* dup_W  = (const float*)d_in[9];
    const float* dup_b  = (const float*)d_in[10];
    const float* out_W  = (const float*)d_in[11];
    const float* out_b  = (const float*)d_in[12];
    float* out = (float*)d_out;

    // ---- workspace layout (86.9 MB; 89.3 MB proven available in R1) ----
    float* ws    = (float*)d_ws;
    float* proj  = ws;                            // 8M f   (x1pre | g)
    float* dbcB  = proj  + (size_t)ROWS*2*D_;     // 327680 f
    float* delta = dbcB  + (size_t)ROWS*NDBC;     // 4M f
    float* scale = delta + (size_t)ROWS*D_;       // 2048 f
    us* hbf   = (us*)(scale + ROWS);              // 2M us
    us* x1cb  = hbf   + (size_t)ROWS*DM_;         // 4M us
    us* dtrb  = x1cb  + (size_t)ROWS*D_;          // 256K us
    us* ybf   = dtrb  + (size_t)ROWS*DTR_;        // 4M us
    us* inWt  = ybf   + (size_t)ROWS*D_;          // 4M us   [4096][1024]
    us* dbcWt = inWt  + (size_t)2*D_*DM_;         // 320K us [160][2048]
    us* dupWt = dbcWt + (size_t)NDBC*D_;          // 256K us [2048][128]
    us* outWt = dupWt + (size_t)D_*DTR_;          // 2M us   [1024][2048]

    dim3 tb(32, 8);
    // weight prep: fp32 [R][C] -> bf16 [C][R]
    transpose_bf<<<dim3(4096/32, 1024/32), tb, 0, stream>>>(in_W,  inWt,  DM_, 2*D_);
    transpose_bf<<<dim3(5,      2048/32), tb, 0, stream>>>(dbc_W, dbcWt, D_,  NDBC);
    transpose_bf<<<dim3(2048/32,      4), tb, 0, stream>>>(dup_W, dupWt, DTR_, D_);
    transpose_bf<<<dim3(1024/32, 2048/32), tb, 0, stream>>>(out_W, outWt, D_,  DM_);

    // rmsnorm -> bf16 A
    rms_scale_kernel<<<ROWS, 256, 0, stream>>>(x, scale);
    hbf_kernel<<<(ROWS*DM_)/256, 256, 0, stream>>>(x, scale, rms_w, hbf);

    // in_proj: proj = h @ in_W + in_b      [2048 x 4096], K=1024
    mgemm<0><<<dim3(4096/128, ROWS/128), 256, 0, stream>>>(
        hbf, inWt, in_b, proj, nullptr, nullptr, ROWS, 2*D_, DM_);

    // conv + silu -> x1c (bf16)
    conv_silu_kernel<<<(ROWS*D_)/256, 256, 0, stream>>>(proj, conv_w, conv_b, x1cb);

    // dbc = x1c @ dbc_W + dbc_b            [2048 x 160], K=2048 (+bf16 aux of cols<128)
    mgemm<3><<<dim3(2, ROWS/128), 256, 0, stream>>>(
        x1cb, dbcWt, dbc_b, dbcB, dtrb, nullptr, ROWS, NDBC, D_);

    // delta = softplus(dtr @ dup_W + dup_b)  [2048 x 2048], K=128
    mgemm<1><<<dim3(2048/128, ROWS/128), 256, 0, stream>>>(
        dtrb, dupWt, dup_b, delta, nullptr, nullptr, ROWS, D_, DTR_);

    // chunked selective scan + gate -> ybf
    scan_block_kernel<<<B_*D_, 256, 0, stream>>>(delta, x1cb, dbcB, A_log, proj, ybf);

    // out = y @ out_W + out_b + residual   [2048 x 1024], K=2048
    mgemm<2><<<dim3(1024/128, ROWS/128), 256, 0, stream>>>(
        ybf, outWt, out_b, out, nullptr, x, ROWS, DM_, D_);
}

// Round 9
// 464.360 us; speedup vs baseline: 1.6368x; 1.0583x over previous
//
#include <hip/hip_runtime.h>
#include <math.h>

typedef unsigned short us;
typedef __attribute__((ext_vector_type(8))) short frag8;
typedef __attribute__((ext_vector_type(4))) float f4;

#define B_   2
#define T_   1024
#define DM_  1024
#define D_   2048
#define N_   16
#define DTR_ 128
#define NDBC 160           // DTR + 2N
#define ROWS (B_*T_)       // 2048
#define EPS_ 1e-6f
#define NCH  16            // scan chunks per channel
#define CLEN (T_/NCH)      // 64 steps per chunk

__device__ __forceinline__ float us2f(us s){
    return __uint_as_float(((unsigned int)s) << 16);
}
__device__ __forceinline__ us f2us(float f){   // RTN-even fp32->bf16
    unsigned int u = __float_as_uint(f);
    return (us)((u + 0x7FFF + ((u >> 16) & 1)) >> 16);
}

// ------------- weight prep: transpose fp32 [R][C] -> bf16 [C][R] -------------
__global__ __launch_bounds__(256) void transpose_bf(const float* __restrict__ in,
                                                    us* __restrict__ out, int R, int C)
{
    __shared__ us tile[32][33];
    int c0 = blockIdx.x * 32, r0 = blockIdx.y * 32;
    int tx = threadIdx.x, ty = threadIdx.y;   // 32 x 8
    for (int i = ty; i < 32; i += 8) {
        int r = r0 + i, c = c0 + tx;
        tile[i][tx] = (r < R && c < C) ? f2us(in[(size_t)r * C + c]) : (us)0;
    }
    __syncthreads();
    for (int i = ty; i < 32; i += 8) {
        int c = c0 + i, r = r0 + tx;
        if (c < C && r < R) out[(size_t)c * R + r] = tile[tx][i];
    }
}

// ------------- bf16 [R][C] -> bf16 [C][R] (dims multiples of 32) -------------
__global__ __launch_bounds__(256) void transpose_us(const us* __restrict__ in,
                                                    us* __restrict__ out, int R, int C)
{
    __shared__ us tile[32][33];
    int c0 = blockIdx.x * 32, r0 = blockIdx.y * 32;
    int tx = threadIdx.x, ty = threadIdx.y;   // 32 x 8
    for (int i = ty; i < 32; i += 8)
        tile[i][tx] = in[(size_t)(r0 + i) * C + c0 + tx];
    __syncthreads();
    for (int i = ty; i < 32; i += 8)
        out[(size_t)(c0 + i) * R + r0 + tx] = tile[tx][i];
}

// ---------------- RMS scale: x (fp32) -> scale[row] ----------------
__global__ __launch_bounds__(256) void rms_scale_kernel(const float* __restrict__ x,
                                                        float* __restrict__ scale)
{
    const int row = blockIdx.x;
    const float* xr = x + (size_t)row * DM_;
    const int tid = threadIdx.x;
    float ss = 0.f;
#pragma unroll
    for (int i = 0; i < 4; ++i) { float v = xr[tid + i*256]; ss += v*v; }
#pragma unroll
    for (int off = 32; off >= 1; off >>= 1) ss += __shfl_xor(ss, off, 64);
    __shared__ float red[4];
    if ((tid & 63) == 0) red[tid >> 6] = ss;
    __syncthreads();
    if (tid == 0) {
        float tot = red[0] + red[1] + red[2] + red[3];
        scale[row] = rsqrtf(tot / (float)DM_ + EPS_);
    }
}

// ---------------- rmsnorm apply -> bf16 A for in_proj ----------------
__global__ __launch_bounds__(256) void hbf_kernel(const float* __restrict__ x,
                                                  const float* __restrict__ scale,
                                                  const float* __restrict__ rms_w,
                                                  us* __restrict__ hbf)
{
    int idx = blockIdx.x * 256 + threadIdx.x;       // ROWS*DM
    int row = idx >> 10, k = idx & (DM_ - 1);
    hbf[idx] = f2us(x[idx] * scale[row] * rms_w[k]);
}

// ---------- MFMA GEMM: C[M,N] = A[M,K](bf16) * Bt[N,K](bf16)^T + bias --------
// 128x128 tile / 4 waves; wave 64x64 via 4x4 mfma_f32_16x16x32_bf16.
// EPI 1: softplus -> TRANSPOSED fp32 store Cf[col*ROWS+row]  (delta_t)
// EPI 2: +resid -> fp32 row-major (out)
// EPI 3: fp32 row-major + bf16 aux for col<DTR (dbc + dtrb)
// EPI 4: col<D -> fp32 x1pre[row*D+col]; col>=D -> fp32 g_t[(col-D)*ROWS+row]
template<int EPI>
__global__ __launch_bounds__(256) void mgemm(
    const us*    __restrict__ A,     // [M][K]
    const us*    __restrict__ Bt,    // [N][K]
    const float* __restrict__ bias,  // [N]
    float*       __restrict__ Cf,
    float*       __restrict__ Cf2,   // EPI==4: g_t
    us*          __restrict__ Caux,  // EPI==3
    const float* __restrict__ resid, // EPI==2
    int M, int N, int K)
{
    __shared__ us As[128][72];   // 72-short rows: b128 frag reads 2-way (free)
    __shared__ us Bs[128][72];
    const int tid = threadIdx.x;
    const int bm = blockIdx.y * 128;
    const int bn = blockIdx.x * 128;
    const int w = tid >> 6, lane = tid & 63;
    const int wr = w >> 1, wc = w & 1;
    const int m16 = lane & 15, quad = lane >> 4;

    f4 acc[4][4];
#pragma unroll
    for (int i = 0; i < 4; ++i)
#pragma unroll
        for (int j = 0; j < 4; ++j)
            acc[i][j] = (f4){0.f, 0.f, 0.f, 0.f};

    for (int k0 = 0; k0 < K; k0 += 64) {
        __syncthreads();
#pragma unroll
        for (int i = 0; i < 4; ++i) {
            int chunk = i * 256 + tid;           // 1024 chunks of 16B
            int row = chunk >> 3, c8 = (chunk & 7) * 8;
            int4 va = *(const int4*)(A + (size_t)(bm + row) * K + k0 + c8);
            *(int4*)&As[row][c8] = va;
            int nrow = bn + row;
            int4 vb = make_int4(0, 0, 0, 0);
            if (nrow < N) vb = *(const int4*)(Bt + (size_t)nrow * K + k0 + c8);
            *(int4*)&Bs[row][c8] = vb;
        }
        __syncthreads();
#pragma unroll
        for (int ks = 0; ks < 64; ks += 32) {
            frag8 af[4], bfr[4];
#pragma unroll
            for (int i = 0; i < 4; ++i)
                af[i] = *(const frag8*)&As[wr*64 + i*16 + m16][ks + quad*8];
#pragma unroll
            for (int j = 0; j < 4; ++j)
                bfr[j] = *(const frag8*)&Bs[wc*64 + j*16 + m16][ks + quad*8];
#pragma unroll
            for (int i = 0; i < 4; ++i)
#pragma unroll
                for (int j = 0; j < 4; ++j)
                    acc[i][j] = __builtin_amdgcn_mfma_f32_16x16x32_bf16(af[i], bfr[j], acc[i][j], 0, 0, 0);
        }
    }

#pragma unroll
    for (int i = 0; i < 4; ++i) {
#pragma unroll
        for (int j = 0; j < 4; ++j) {
            int col = bn + wc*64 + j*16 + m16;
            if (col >= N) continue;
            float bv = bias[col];
#pragma unroll
            for (int r = 0; r < 4; ++r) {
                int row = bm + wr*64 + i*16 + quad*4 + r;
                float v = acc[i][j][r] + bv;
                if constexpr (EPI == 1) {
                    v = fmaxf(v, 0.f) + log1pf(expf(-fabsf(v)));   // softplus
                    Cf[(size_t)col * ROWS + row] = v;              // delta_t
                } else if constexpr (EPI == 2) {
                    v += resid[(size_t)row * N + col];
                    Cf[(size_t)row * N + col] = v;
                } else if constexpr (EPI == 3) {
                    Cf[(size_t)row * N + col] = v;
                    if (col < DTR_) Caux[(size_t)row * DTR_ + col] = f2us(v);
                } else if constexpr (EPI == 4) {
                    if (col < D_) Cf [(size_t)row * D_ + col] = v;          // x1pre
                    else          Cf2[(size_t)(col - D_) * ROWS + row] = v; // g_t
                }
            }
        }
    }
}

// ---------------- depthwise causal conv (K=4) + SiLU -> bf16 -----------------
// reads x1pre [ROWS][D], writes x1cb [ROWS][D] (bf16)
__global__ __launch_bounds__(256) void conv_silu_kernel(
    const float* __restrict__ x1pre,
    const float* __restrict__ cw,
    const float* __restrict__ cb,
    us*          __restrict__ x1cb)
{
    int idx = blockIdx.x * 256 + threadIdx.x;   // ROWS*D
    int d   = idx & (D_ - 1);
    int row = idx >> 11;
    int t   = row & (T_ - 1);
    const float* base = x1pre + (size_t)row * D_ + d;
    float acc = cb[d];
    float w0 = cw[d*4+0], w1 = cw[d*4+1], w2 = cw[d*4+2], w3 = cw[d*4+3];
    acc = fmaf(w3, base[0], acc);
    if (t >= 1) acc = fmaf(w2, base[-D_],   acc);
    if (t >= 2) acc = fmaf(w1, base[-2*D_], acc);
    if (t >= 3) acc = fmaf(w0, base[-3*D_], acc);
    float sg = 1.f / (1.f + __expf(-acc));
    x1cb[idx] = f2us(acc * sg);
}

// ------- chunked selective scan + gate, one block per (b,d) channel ----------
// All global streams unit-stride: delta_t/g_t [d][rows] fp32, x1tb [d][rows]
// bf16, y -> LDS -> y_t [d][rows] bf16. B/C from dbcB (L2-resident).
__global__ __launch_bounds__(256) void scan_block_kernel(
    const float* __restrict__ delta_t,
    const us*    __restrict__ x1tb,
    const float* __restrict__ dbc,    // [...,128:144]=Bm [...,144:160]=Cm
    const float* __restrict__ A_log,
    const float* __restrict__ g_t,
    us*          __restrict__ y_t)
{
    __shared__ float dvs[T_ + NCH];   // swizzle f(t)=t+(t>>6)
    __shared__ float xvs[T_ + NCH];
    __shared__ float gs [T_ + NCH];
    __shared__ float ys [T_ + NCH];
    __shared__ float Pl[NCH][N_];
    __shared__ float Sl[NCH][N_];

    const int tid = threadIdx.x;
    const int d = blockIdx.x & (D_ - 1);
    const int b = blockIdx.x >> 11;
    const int n = tid & 15;
    const int c = tid >> 4;
    const size_t rb = (size_t)b * T_;
    const size_t cb0 = (size_t)d * ROWS + rb;     // channel base in [d][rows]

    {   // vectorized coalesced staging: 4 elems/thread
        int i = tid * 4;
        int fi = i + (i >> 6);
        *(float4*)&dvs[fi] = *(const float4*)&delta_t[cb0 + i];
        *(float4*)&gs [fi] = *(const float4*)&g_t    [cb0 + i];
        ushort4 ux = *(const ushort4*)&x1tb[cb0 + i];
        xvs[fi+0] = us2f(ux.x); xvs[fi+1] = us2f(ux.y);
        xvs[fi+2] = us2f(ux.z); xvs[fi+3] = us2f(ux.w);
    }
    const float a_coef = -__expf(A_log[d * N_ + n]);
    __syncthreads();

    float P = 1.f, S = 0.f;
    const int t0 = c * CLEN;
    for (int j = 0; j < CLEN; ++j) {
        int t = t0 + j;
        int ft = t + (t >> 6);
        float dv = dvs[ft];
        float xv = xvs[ft];
        float Bv = dbc[(rb + t) * NDBC + DTR_ + n];
        float a = __expf(dv * a_coef);
        P *= a;
        S = fmaf(a, S, dv * Bv * xv);
    }
    Pl[c][n] = P;
    Sl[c][n] = S;
    __syncthreads();

    float h = 0.f;
    for (int c2 = 0; c2 < c; ++c2)
        h = fmaf(Pl[c2][n], h, Sl[c2][n]);

    for (int j = 0; j < CLEN; ++j) {
        int t = t0 + j;
        int ft = t + (t >> 6);
        float dv = dvs[ft];
        float xv = xvs[ft];
        size_t r = rb + t;
        float Bv = dbc[r * NDBC + DTR_ + n];
        float Cv = dbc[r * NDBC + DTR_ + N_ + n];
        float a = __expf(dv * a_coef);
        h = fmaf(a, h, dv * Bv * xv);
        float part = h * Cv;
        part += __shfl_xor(part, 1, 16);
        part += __shfl_xor(part, 2, 16);
        part += __shfl_xor(part, 4, 16);
        part += __shfl_xor(part, 8, 16);
        if (n == 0) {
            float g = gs[ft];
            float sg = 1.f / (1.f + __expf(-g));
            ys[ft] = part * g * sg;
        }
    }
    __syncthreads();
    {   // coalesced bf16 store of y
        int i = tid * 4;
        int fi = i + (i >> 6);
        ushort4 uy;
        uy.x = f2us(ys[fi+0]); uy.y = f2us(ys[fi+1]);
        uy.z = f2us(ys[fi+2]); uy.w = f2us(ys[fi+3]);
        *(ushort4*)&y_t[cb0 + i] = uy;
    }
}

extern "C" void kernel_launch(void* const* d_in, const int* in_sizes, int n_in,
                              void* d_out, int out_size, void* d_ws, size_t ws_size,
                              hipStream_t stream)
{
    const float* x      = (const float*)d_in[0];
    const float* rms_w  = (const float*)d_in[1];
    const float* in_W   = (const float*)d_in[2];
    const float* in_b   = (const float*)d_in[3];
    const float* conv_w = (const float*)d_in[4];
    const float* conv_b = (const float*)d_in[5];
    const float* A_log  = (const float*)d_in[6];
    const float* dbc_W  = (const float*)d_in[7];
    const float* dbc_b  = (const float*)d_in[8];
    const float* dup_W  = (const float*)d_in[9];
    const float* dup_b  = (const float*)d_in[10];
    const float* out_W  = (const float*)d_in[11];
    const float* out_b  = (const float*)d_in[12];
    float* out = (float*)d_out;

    // ---- workspace layout (~83 MB; 86.9 MB proven available) ----
    float* ws      = (float*)d_ws;
    float* x1pre   = ws;                           // 4M f (16 MB) dead after conv
    float* g_t     = x1pre  + (size_t)ROWS*D_;     // 4M f (16 MB) [d][rows]
    float* dbcB    = g_t    + (size_t)ROWS*D_;     // 320K f
    float* delta_t = dbcB   + (size_t)ROWS*NDBC;   // 4M f (16 MB) [d][rows]
    float* scale   = delta_t+ (size_t)ROWS*D_;     // 2K f
    us* hbf   = (us*)(scale + ROWS);               // 2M us (4 MB)
    us* x1cb  = hbf   + (size_t)ROWS*DM_;          // 4M us (8 MB) [rows][D]
    us* dtrb  = x1cb  + (size_t)ROWS*D_;           // 256K us
    us* ybf   = dtrb  + (size_t)ROWS*DTR_;         // 4M us (8 MB) [rows][D]
    us* inWt  = ybf   + (size_t)ROWS*D_;           // 4M us   [4096][1024]
    us* dbcWt = inWt  + (size_t)2*D_*DM_;          // 320K us [160][2048]
    us* dupWt = dbcWt + (size_t)NDBC*D_;           // 256K us [2048][128]
    us* outWt = dupWt + (size_t)D_*DTR_;           // 2M us   [1024][2048]
    // aliases into dead x1pre (16 MB): x1tb (8 MB) + y_t (8 MB)
    us* x1tb = (us*)x1pre;                         // [d][rows] bf16, written after conv
    us* y_t  = x1tb + (size_t)ROWS*D_;             // [d][rows] bf16, written by scan

    dim3 tb(32, 8);
    // weight prep: fp32 [R][C] -> bf16 [C][R]
    transpose_bf<<<dim3(4096/32, 1024/32), tb, 0, stream>>>(in_W,  inWt,  DM_, 2*D_);
    transpose_bf<<<dim3(5,      2048/32), tb, 0, stream>>>(dbc_W, dbcWt, D_,  NDBC);
    transpose_bf<<<dim3(2048/32,      4), tb, 0, stream>>>(dup_W, dupWt, DTR_, D_);
    transpose_bf<<<dim3(1024/32, 2048/32), tb, 0, stream>>>(out_W, outWt, D_,  DM_);

    // rmsnorm -> bf16 A
    rms_scale_kernel<<<ROWS, 256, 0, stream>>>(x, scale);
    hbf_kernel<<<(ROWS*DM_)/256, 256, 0, stream>>>(x, scale, rms_w, hbf);

    // in_proj: x1pre[rows][D] + g_t[d][rows]      [2048 x 4096], K=1024
    mgemm<4><<<dim3(4096/128, ROWS/128), 256, 0, stream>>>(
        hbf, inWt, in_b, x1pre, g_t, nullptr, nullptr, ROWS, 2*D_, DM_);

    // conv + silu -> x1cb [rows][D] bf16
    conv_silu_kernel<<<(ROWS*D_)/256, 256, 0, stream>>>(x1pre, conv_w, conv_b, x1cb);

    // dbc = x1c @ dbc_W + dbc_b  [2048 x 160], K=2048 (+bf16 aux cols<128)
    mgemm<3><<<dim3(2, ROWS/128), 256, 0, stream>>>(
        x1cb, dbcWt, dbc_b, dbcB, nullptr, dtrb, nullptr, ROWS, NDBC, D_);

    // x1cb -> x1tb [d][rows]   (x1pre now dead)
    transpose_us<<<dim3(D_/32, ROWS/32), tb, 0, stream>>>(x1cb, x1tb, ROWS, D_);

    // delta_t = softplus(dtr @ dup_W + dup_b)^T   [2048 x 2048], K=128
    mgemm<1><<<dim3(2048/128, ROWS/128), 256, 0, stream>>>(
        dtrb, dupWt, dup_b, delta_t, nullptr, nullptr, nullptr, ROWS, D_, DTR_);

    // chunked selective scan + gate -> y_t [d][rows]
    scan_block_kernel<<<B_*D_, 256, 0, stream>>>(delta_t, x1tb, dbcB, A_log, g_t, y_t);

    // y_t -> ybf [rows][D]
    transpose_us<<<dim3(ROWS/32, D_/32), tb, 0, stream>>>(y_t, ybf, D_, ROWS);

    // out = y @ out_W + out_b + residual   [2048 x 1024], K=2048
    mgemm<2><<<dim3(1024/128, ROWS/128), 256, 0, stream>>>(
        ybf, outWt, out_b, out, nullptr, nullptr, x, ROWS, DM_, D_);
}